// Round 13
// baseline (91.132 us; speedup 1.0000x reference)
//
#include <hip/hip_runtime.h>
#include <hip/hip_bf16.h>

#define NN 4096
#define SJ 8
#define JCH (NN / SJ)        // 512
#define JSTEP 64
#define NSTEPS (JCH / JSTEP) // 8
#define LOG2E 1.44269504f

typedef __attribute__((ext_vector_type(4))) float f32x4;
typedef __attribute__((ext_vector_type(4))) int i32x4;
typedef __attribute__((ext_vector_type(4))) unsigned int u32x4;
typedef __attribute__((ext_vector_type(8))) short short8;
typedef __attribute__((ext_vector_type(8))) _Float16 f16x8;

// packed bf16 pair (k1 GEMM input conversion only)
__device__ __forceinline__ unsigned pk2(float a, float b) {
    float2 t; t.x = a; t.y = b;
    __hip_bfloat162 h = __float22bfloat162_rn(t);
    unsigned r;
    __builtin_memcpy(&r, &h, 4);
    return r;
}
// packed f16 pair, RNE (v_cvt_f16_f32 x2 + pack)
__device__ __forceinline__ unsigned pkh(float a, float b) {
    unsigned short lo = __builtin_bit_cast(unsigned short, (_Float16)a);
    unsigned short hi = __builtin_bit_cast(unsigned short, (_Float16)b);
    return (unsigned)lo | ((unsigned)hi << 16);
}

__device__ __forceinline__ short8 load8_bf(const float* __restrict__ p) {
    f32x4 a = *(const f32x4*)p;
    f32x4 b = *(const f32x4*)(p + 4);
    u32x4 v = {pk2(a[0], a[1]), pk2(a[2], a[3]), pk2(b[0], b[1]), pk2(b[2], b[3])};
    return __builtin_bit_cast(short8, v);
}

// Kernel 1: h = x @ W^T (bf16 MFMA). Epilogue (f16 tables, RNE):
//   Rt[h][i] = exp(-0.8*es_i) f32    (exp(es) cancels in softmax)
//   Bf[h][j] = f16(exp(ed_j)), Df[h][j] = f16(exp(0.2*ed_j))
//   hf[h*32+d][j] = f16 h, transposed via per-wave LDS tile (coalesced stores)
__global__ __launch_bounds__(256) void k1_proj(
        const float* __restrict__ x, const float* __restrict__ W,
        const float* __restrict__ asrc, const float* __restrict__ adst,
        unsigned short* __restrict__ hf, float* __restrict__ Rt,
        unsigned short* __restrict__ Bf, unsigned short* __restrict__ Df) {
    __shared__ unsigned short ttile[4][32][16];   // 4 KB
    const int ibase = blockIdx.x * 16;
    const int w = threadIdx.x >> 6;
    const int lane = threadIdx.x & 63;
    const int grp = lane >> 4, li = lane & 15;

    const float* xrow = x + (ibase + li) * 128;
    const float* w0 = W + (w * 32 + li) * 128;
    const float* w1 = W + (w * 32 + 16 + li) * 128;

    f32x4 c0 = {0.f, 0.f, 0.f, 0.f}, c1 = {0.f, 0.f, 0.f, 0.f};
#pragma unroll
    for (int ko = 0; ko < 128; ko += 32) {
        const int kk = ko + grp * 8;
        short8 a = load8_bf(xrow + kk);
        short8 b0 = load8_bf(w0 + kk);
        short8 b1 = load8_bf(w1 + kk);
        c0 = __builtin_amdgcn_mfma_f32_16x16x32_bf16(a, b0, c0, 0, 0, 0);
        c1 = __builtin_amdgcn_mfma_f32_16x16x32_bf16(a, b1, c1, 0, 0, 0);
    }
    const float as0 = asrc[w * 32 + li], as1 = asrc[w * 32 + 16 + li];
    const float ad0 = adst[w * 32 + li], ad1 = adst[w * 32 + 16 + li];
    float pes[4], ped[4];
#pragma unroll
    for (int r = 0; r < 4; ++r) {
        pes[r] = c0[r] * as0 + c1[r] * as1;
        ped[r] = c0[r] * ad0 + c1[r] * ad1;
    }
#pragma unroll
    for (int m = 1; m < 16; m <<= 1) {
#pragma unroll
        for (int r = 0; r < 4; ++r) {
            pes[r] += __shfl_xor(pes[r], m);
            ped[r] += __shfl_xor(ped[r], m);
        }
    }
    if (li == 0) {
#pragma unroll
        for (int r = 0; r < 4; ++r) {
            const int row = ibase + grp * 4 + r;
            Rt[w * NN + row] = __builtin_amdgcn_exp2f(-0.8f * LOG2E * pes[r]);
            const float Bv = __builtin_amdgcn_exp2f(LOG2E * ped[r]);
            const float Dv = __builtin_amdgcn_exp2f(0.2f * LOG2E * ped[r]);
            Bf[w * NN + row] = __builtin_bit_cast(unsigned short, (_Float16)Bv);
            Df[w * NN + row] = __builtin_bit_cast(unsigned short, (_Float16)Dv);
        }
    }
    unsigned short* tw = &ttile[w][0][0];
    {
        uint2 v0; v0.x = pkh(c0[0], c0[1]); v0.y = pkh(c0[2], c0[3]);
        uint2 v1; v1.x = pkh(c1[0], c1[1]); v1.y = pkh(c1[2], c1[3]);
        *(uint2*)&tw[li * 16 + grp * 4] = v0;
        *(uint2*)&tw[(li + 16) * 16 + grp * 4] = v1;
    }
    __syncthreads();
    const int d = lane >> 1, half = lane & 1;
    u32x4 v = *(const u32x4*)&ttile[w][d][half * 8];
    *(u32x4*)(hf + (size_t)(w * 32 + d) * NN + ibase + half * 8) = v;
}

// volatile 16B load with compile-time immediate offset (zero addressing VALU)
template<int OFF>
__device__ __forceinline__ u32x4 gld(const void* p) {
    u32x4 d;
    asm volatile("global_load_dwordx4 %0, %1, off offset:%c2"
                 : "=&v"(d) : "v"(p), "n"(OFF));
    return d;
}

// per-step payload: 12 x u32x4 = 48 VGPR
struct SLOT { u32x4 q00, q01, q10, q11, t00, t01, t10, t11, b0, b1, d0, d1; };

#define LOADSET(S, TT) do {                                                    \
    (S).q00 = gld<(TT)*256 +   0>(aB);  (S).q01 = gld<(TT)*256 +  16>(aB);     \
    (S).q10 = gld<(TT)*256 + 128>(aB);  (S).q11 = gld<(TT)*256 + 144>(aB);     \
    (S).t00 = gld<(TT)*128 +   0>(h0b); (S).t01 = gld<(TT)*128 +  64>(h0b);    \
    (S).t10 = gld<(TT)*128 +   0>(h1b); (S).t11 = gld<(TT)*128 +  64>(h1b);    \
    (S).b0  = gld<(TT)*128 +   0>(Bb);  (S).b1  = gld<(TT)*128 +  64>(Bb);     \
    (S).d0  = gld<(TT)*128 +   0>(Db);  (S).d1  = gld<(TT)*128 +  64>(Db);     \
} while (0)

#define LAUNDER(S) asm volatile("" : "+v"((S).q00), "+v"((S).q01),             \
    "+v"((S).q10), "+v"((S).q11), "+v"((S).t00), "+v"((S).t01),                \
    "+v"((S).t10), "+v"((S).t11), "+v"((S).b0), "+v"((S).b1),                  \
    "+v"((S).d0), "+v"((S).d1))

// pair op: P2 = adj ? max(B, R*D) : 0  (packed f16: mul, max, perm-mask, and)
__device__ __forceinline__ unsigned pmm(unsigned Rp, unsigned B2, unsigned D2,
                                        unsigned a0, unsigned a1) {
    unsigned rd, mx;
    asm("v_pk_mul_f16 %0, %1, %2" : "=v"(rd) : "v"(Rp), "v"(D2));
    asm("v_pk_max_f16 %0, %1, %2" : "=v"(mx) : "v"(B2), "v"(rd));
    const unsigned mask = __builtin_amdgcn_perm(0u - a1, 0u - a0, 0x05040100u);
    return mx & mask;
}

__device__ __forceinline__ f16x8 buildA(unsigned Rp, const u32x4 B, const u32x4 D,
                                        const u32x4 q0, const u32x4 q1) {
    u32x4 w;
    w[0] = pmm(Rp, B[0], D[0], q0[0], q0[1]);
    w[1] = pmm(Rp, B[1], D[1], q0[2], q0[3]);
    w[2] = pmm(Rp, B[2], D[2], q1[0], q1[1]);
    w[3] = pmm(Rp, B[3], D[3], q1[2], q1[3]);
    return __builtin_bit_cast(f16x8, w);
}

// Kernel 3: grid (256 i-tiles of 16 rows, SJ) x 256 thr. Wave = head, fully
// private: NO LDS, NO BARRIERS. adj/hT/B/D -> registers via volatile-asm
// loads with immediate offsets; 3 rotating slots, depth-2, vmcnt(12)+launder.
// The block's 4 waves read identical adj addresses -> L1 broadcast.
__global__ __launch_bounds__(256) void k3_main(
        const int* __restrict__ adj, const unsigned short* __restrict__ hf,
        const float* __restrict__ Rt, const unsigned short* __restrict__ Bf,
        const unsigned short* __restrict__ Df,
        float* __restrict__ numer, float* __restrict__ denom) {
    const int ibase = blockIdx.x * 16;
    const int jstart = blockIdx.y * JCH;
    const int head = threadIdx.x >> 6;
    const int lane = threadIdx.x & 63;
    const int grp = lane >> 4, li = lane & 15;

    const float Rv = Rt[head * NN + ibase + li];
    const unsigned short ru = __builtin_bit_cast(unsigned short, (_Float16)Rv);
    const unsigned Rp = (unsigned)ru | ((unsigned)ru << 16);

    const int* aB = adj + (size_t)(ibase + li) * NN + jstart + grp * 8;
    const unsigned short* h0b = hf + (size_t)(head * 32 + li) * NN + jstart + grp * 8;
    const unsigned short* h1b = h0b + (size_t)16 * NN;
    const unsigned short* Bb = Bf + head * NN + jstart + grp * 8;
    const unsigned short* Db = Df + head * NN + jstart + grp * 8;

    f32x4 c0 = {0.f,0.f,0.f,0.f}, c1 = {0.f,0.f,0.f,0.f}, dn = {0.f,0.f,0.f,0.f};
    u32x4 onesw = {0x3C003C00u, 0x3C003C00u, 0x3C003C00u, 0x3C003C00u};
    const f16x8 ones = __builtin_bit_cast(f16x8, onesw);

    SLOT s0, s1, s2;

#define COMPUTE(S) do {                                                        \
    _Pragma("unroll")                                                          \
    for (int ks = 0; ks < 2; ++ks) {                                           \
        const u32x4 ba = ks ? (S).b1 : (S).b0;                                 \
        const u32x4 da = ks ? (S).d1 : (S).d0;                                 \
        const u32x4 qa = ks ? (S).q10 : (S).q00;                               \
        const u32x4 qb = ks ? (S).q11 : (S).q01;                               \
        const f16x8 tA = __builtin_bit_cast(f16x8, ks ? (S).t01 : (S).t00);    \
        const f16x8 tB = __builtin_bit_cast(f16x8, ks ? (S).t11 : (S).t10);    \
        const f16x8 A = buildA(Rp, ba, da, qa, qb);                            \
        c0 = __builtin_amdgcn_mfma_f32_16x16x32_f16(A, tA, c0, 0, 0, 0);       \
        c1 = __builtin_amdgcn_mfma_f32_16x16x32_f16(A, tB, c1, 0, 0, 0);       \
        dn = __builtin_amdgcn_mfma_f32_16x16x32_f16(A, ones, dn, 0, 0, 0);     \
    }                                                                          \
} while (0)

#define STEP(T, CUR, NXT, FAR) do {                                            \
    if ((T) + 2 < NSTEPS) { LOADSET(FAR, (T) + 2); }                           \
    __builtin_amdgcn_sched_barrier(0);                                         \
    COMPUTE(CUR);                                                              \
    if ((T) + 1 < NSTEPS) {                                                    \
        if ((T) + 2 < NSTEPS) {                                                \
            asm volatile("s_waitcnt vmcnt(12)" ::: "memory");                  \
        } else {                                                               \
            asm volatile("s_waitcnt vmcnt(0)" ::: "memory");                   \
        }                                                                      \
        LAUNDER(NXT);                                                          \
        __builtin_amdgcn_sched_barrier(0);                                     \
    }                                                                          \
} while (0)

    // prologue: sets 0 and 1 in flight (12 each), drain set0
    LOADSET(s0, 0);
    __builtin_amdgcn_sched_barrier(0);
    LOADSET(s1, 1);
    __builtin_amdgcn_sched_barrier(0);
    asm volatile("s_waitcnt vmcnt(12)" ::: "memory");
    LAUNDER(s0);
    __builtin_amdgcn_sched_barrier(0);

    STEP(0, s0, s1, s2);
    STEP(1, s1, s2, s0);
    STEP(2, s2, s0, s1);
    STEP(3, s0, s1, s2);
    STEP(4, s1, s2, s0);
    STEP(5, s2, s0, s1);
    STEP(6, s0, s1, s2);
    STEP(7, s1, s2, s0);

    // Epilogue: C layout col=li, row=grp*4+r.
    const int r0 = ibase + grp * 4;
    float* nb = numer + head * 32 + li;
#pragma unroll
    for (int r = 0; r < 4; ++r) {
        atomicAdd(nb + (size_t)(r0 + r) * 128, c0[r]);
        atomicAdd(nb + (size_t)(r0 + r) * 128 + 16, c1[r]);
    }
    if (li == 0) {
#pragma unroll
        for (int r = 0; r < 4; ++r)
            atomicAdd(denom + (r0 + r) * 4 + head, dn[r]);
    }
#undef STEP
#undef COMPUTE
}

// Kernel 4: out = numer / denom
__global__ __launch_bounds__(256) void k4_fin(const float* __restrict__ numer,
                                              const float* __restrict__ denom,
                                              float* __restrict__ out) {
    const int idx = blockIdx.x * 256 + threadIdx.x;
    const int node = idx >> 7;
    const int headc = (idx & 127) >> 5;
    out[idx] = numer[idx] / denom[node * 4 + headc];
}

extern "C" void kernel_launch(void* const* d_in, const int* in_sizes, int n_in,
                              void* d_out, int out_size, void* d_ws, size_t ws_size,
                              hipStream_t stream) {
    const float* x = (const float*)d_in[0];
    const int* adj = (const int*)d_in[1];
    const float* W = (const float*)d_in[2];
    const float* asrc = (const float*)d_in[3];
    const float* adst = (const float*)d_in[4];
    float* out = (float*)d_out;

    char* ws = (char*)d_ws;
    float* numer = (float*)ws;                                          // 2 MB
    float* denom = (float*)(ws + (size_t)2097152);                      // 64 KB
    float* Rt = (float*)(ws + (size_t)2162688);                         // 64 KB
    unsigned short* Bf = (unsigned short*)(ws + (size_t)2228224);       // 32 KB
    unsigned short* Df = (unsigned short*)(ws + (size_t)2260992);       // 32 KB
    unsigned short* hf = (unsigned short*)(ws + (size_t)2293760);       // 1 MB

    (void)hipMemsetAsync(numer, 0, 2097152 + 65536, stream);            // zero accumulators
    k1_proj<<<256, 256, 0, stream>>>(x, W, asrc, adst, hf, Rt, Bf, Df);
    k3_main<<<dim3(256, SJ), 256, 0, stream>>>(adj, hf, Rt, Bf, Df, numer, denom);
    k4_fin<<<2048, 256, 0, stream>>>(numer, denom, out);
}

// Round 14
// 70.380 us; speedup vs baseline: 1.2949x; 1.2949x over previous
//
#include <hip/hip_runtime.h>
#include <hip/hip_bf16.h>

#define NN 4096
#define SJ 8
#define JCH (NN / SJ)        // 512
#define JSTEP 64
#define NSTEPS (JCH / JSTEP) // 8
#define LOG2E 1.44269504f

typedef __attribute__((ext_vector_type(4))) float f32x4;
typedef __attribute__((ext_vector_type(4))) int i32x4;
typedef __attribute__((ext_vector_type(4))) unsigned int u32x4;
typedef __attribute__((ext_vector_type(8))) short short8;

// packed bf16 pair: (lo=bf16(a), hi=bf16(b)) in one dword (v_cvt_pk_bf16_f32)
__device__ __forceinline__ unsigned pk2(float a, float b) {
    float2 t; t.x = a; t.y = b;
    __hip_bfloat162 h = __float22bfloat162_rn(t);
    unsigned r;
    __builtin_memcpy(&r, &h, 4);
    return r;
}

__device__ __forceinline__ short8 load8_bf(const float* __restrict__ p) {
    f32x4 a = *(const f32x4*)p;
    f32x4 b = *(const f32x4*)(p + 4);
    u32x4 v = {pk2(a[0], a[1]), pk2(a[2], a[3]), pk2(b[0], b[1]), pk2(b[2], b[3])};
    return __builtin_bit_cast(short8, v);
}

// Kernel 1: h = x @ W^T (bf16 MFMA). Epilogue:
//   Rt[h][i]  = exp(-0.8*es_i)   (f32; exp(es) factor cancels in softmax)
//   BDt[h][j] = pack_bf16(exp(ed_j), exp(0.2*ed_j))
//   hT[h*32+d][j] = bf16 h, transposed via per-wave LDS tile (coalesced stores)
__global__ __launch_bounds__(256) void k1_proj(
        const float* __restrict__ x, const float* __restrict__ W,
        const float* __restrict__ asrc, const float* __restrict__ adst,
        unsigned short* __restrict__ hT, float* __restrict__ Rt,
        unsigned* __restrict__ BDt) {
    __shared__ unsigned short ttile[4][32][16];   // 4 KB
    const int ibase = blockIdx.x * 16;
    const int w = threadIdx.x >> 6;
    const int lane = threadIdx.x & 63;
    const int grp = lane >> 4, li = lane & 15;

    const float* xrow = x + (ibase + li) * 128;
    const float* w0 = W + (w * 32 + li) * 128;
    const float* w1 = W + (w * 32 + 16 + li) * 128;

    f32x4 c0 = {0.f, 0.f, 0.f, 0.f}, c1 = {0.f, 0.f, 0.f, 0.f};
#pragma unroll
    for (int ko = 0; ko < 128; ko += 32) {
        const int kk = ko + grp * 8;
        short8 a = load8_bf(xrow + kk);
        short8 b0 = load8_bf(w0 + kk);
        short8 b1 = load8_bf(w1 + kk);
        c0 = __builtin_amdgcn_mfma_f32_16x16x32_bf16(a, b0, c0, 0, 0, 0);
        c1 = __builtin_amdgcn_mfma_f32_16x16x32_bf16(a, b1, c1, 0, 0, 0);
    }
    const float as0 = asrc[w * 32 + li], as1 = asrc[w * 32 + 16 + li];
    const float ad0 = adst[w * 32 + li], ad1 = adst[w * 32 + 16 + li];
    float pes[4], ped[4];
#pragma unroll
    for (int r = 0; r < 4; ++r) {
        pes[r] = c0[r] * as0 + c1[r] * as1;
        ped[r] = c0[r] * ad0 + c1[r] * ad1;
    }
#pragma unroll
    for (int m = 1; m < 16; m <<= 1) {
#pragma unroll
        for (int r = 0; r < 4; ++r) {
            pes[r] += __shfl_xor(pes[r], m);
            ped[r] += __shfl_xor(ped[r], m);
        }
    }
    if (li == 0) {
#pragma unroll
        for (int r = 0; r < 4; ++r) {
            const int row = ibase + grp * 4 + r;
            Rt[w * NN + row] = __builtin_amdgcn_exp2f(-0.8f * LOG2E * pes[r]);
            const float Bv = __builtin_amdgcn_exp2f(LOG2E * ped[r]);
            const float Dv = __builtin_amdgcn_exp2f(0.2f * LOG2E * ped[r]);
            BDt[w * NN + row] = pk2(Bv, Dv);
        }
    }
    unsigned short* tw = &ttile[w][0][0];
    {
        uint2 v0; v0.x = pk2(c0[0], c0[1]); v0.y = pk2(c0[2], c0[3]);
        uint2 v1; v1.x = pk2(c1[0], c1[1]); v1.y = pk2(c1[2], c1[3]);
        *(uint2*)&tw[li * 16 + grp * 4] = v0;
        *(uint2*)&tw[(li + 16) * 16 + grp * 4] = v1;
    }
    __syncthreads();
    const int d = lane >> 1, half = lane & 1;
    u32x4 v = *(const u32x4*)&ttile[w][d][half * 8];
    *(u32x4*)(hT + (size_t)(w * 32 + d) * NN + ibase + half * 8) = v;
}

// ---- inline-asm 16B loads (volatile: cannot be sunk/reordered vs each other) ----
__device__ __forceinline__ u32x4 gld0(const void* p) {
    u32x4 d; asm volatile("global_load_dwordx4 %0, %1, off" : "=&v"(d) : "v"(p)); return d;
}
__device__ __forceinline__ u32x4 gld16(const void* p) {
    u32x4 d; asm volatile("global_load_dwordx4 %0, %1, off offset:16" : "=&v"(d) : "v"(p)); return d;
}
__device__ __forceinline__ u32x4 gld64(const void* p) {
    u32x4 d; asm volatile("global_load_dwordx4 %0, %1, off offset:64" : "=&v"(d) : "v"(p)); return d;
}
__device__ __forceinline__ u32x4 gld128(const void* p) {
    u32x4 d; asm volatile("global_load_dwordx4 %0, %1, off offset:128" : "=&v"(d) : "v"(p)); return d;
}
__device__ __forceinline__ u32x4 gld144(const void* p) {
    u32x4 d; asm volatile("global_load_dwordx4 %0, %1, off offset:144" : "=&v"(d) : "v"(p)); return d;
}

// per-step table payload: 8 x u32x4 = 32 VGPR per slot
struct SR { u32x4 h0k0, h0k1, h1k0, h1k1, bd00, bd01, bd10, bd11; };

#define LOADR(dst, toff) do {                                             \
    (dst).h0k0 = gld0(h0b + (toff));  (dst).h0k1 = gld64(h0b + (toff));   \
    (dst).h1k0 = gld0(h1b + (toff));  (dst).h1k1 = gld64(h1b + (toff));   \
    (dst).bd00 = gld0(bd + (toff));   (dst).bd01 = gld16(bd + (toff));    \
    (dst).bd10 = gld128(bd + (toff)); (dst).bd11 = gld144(bd + (toff));   \
} while (0)

#define LAUNDER(s) asm volatile("" : "+v"((s).h0k0), "+v"((s).h0k1),      \
    "+v"((s).h1k0), "+v"((s).h1k1), "+v"((s).bd00), "+v"((s).bd01),       \
    "+v"((s).bd10), "+v"((s).bd11))

// q = adj * max(B, R*D) from packed bf16 {B,D} (proven math, f32 compute)
__device__ __forceinline__ short8 buildQ(float R, const u32x4 ba, const u32x4 bb,
                                         const i32x4 q0, const i32x4 q1) {
    float p[8];
#pragma unroll
    for (int e = 0; e < 4; ++e) {
        const unsigned v = ba[e];
        const float B = __builtin_bit_cast(float, v << 16);
        const float D = __builtin_bit_cast(float, v & 0xFFFF0000u);
        const float m = fmaxf(B, R * D);
        p[e] = __builtin_bit_cast(float, __builtin_bit_cast(unsigned, m) & (0u - (unsigned)q0[e]));
    }
#pragma unroll
    for (int e = 0; e < 4; ++e) {
        const unsigned v = bb[e];
        const float B = __builtin_bit_cast(float, v << 16);
        const float D = __builtin_bit_cast(float, v & 0xFFFF0000u);
        const float m = fmaxf(B, R * D);
        p[4 + e] = __builtin_bit_cast(float, __builtin_bit_cast(unsigned, m) & (0u - (unsigned)q1[e]));
    }
    u32x4 u = {pk2(p[0], p[1]), pk2(p[2], p[3]), pk2(p[4], p[5]), pk2(p[6], p[7])};
    return __builtin_bit_cast(short8, u);
}

// Kernel 3: grid (256 i-tiles of 16 rows, SJ) x 256 thr. Wave = head, and each
// wave is FULLY independent: it stages its own 16x64 adj tile into a private
// LDS third (global_load_lds, XOR source-swizzle, triple-buffer, depth-2) and
// prefetches its tables into 2 register slots (volatile asm + launder).
// NO s_barrier anywhere -> waves self-pace on per-wave vmcnt; stalls decorrelate.
__global__ __launch_bounds__(256) void k3_main(
        const int* __restrict__ adj, const unsigned short* __restrict__ hT,
        const float* __restrict__ Rt, const unsigned* __restrict__ BDt,
        float* __restrict__ numer, float* __restrict__ denom) {
    __shared__ unsigned int adjb[4][3][16 * 64];   // per-wave private: 4 x 3 x 4 KB

    const int ibase = blockIdx.x * 16;
    const int jstart = blockIdx.y * JCH;
    const int head = threadIdx.x >> 6;
    const int lane = threadIdx.x & 63;
    const int grp = lane >> 4, li = lane & 15;
    const int sub = lane >> 4, p = lane & 15;     // staging roles (4 rows/issue)

    const float R0 = Rt[head * NN + ibase + li];
    const unsigned short* h0b = hT + (size_t)(head * 32 + li) * NN + jstart + grp * 8;
    const unsigned short* h1b = h0b + (size_t)16 * NN;
    const unsigned* bd = BDt + head * NN + jstart + grp * 8;
    const unsigned int* adju = (const unsigned int*)adj;

    // 4 staging base pointers: issue k covers rows 4k..4k+3; lane = (sub,p):
    // row r = 4k+sub, chunk-position p holds global chunk p ^ (r&15)
    const unsigned int* g[4];
#pragma unroll
    for (int k = 0; k < 4; ++k) {
        const int r = k * 4 + sub;
        g[k] = adju + (size_t)(ibase + r) * NN + jstart + (p ^ (r & 15)) * 4;
    }

    f32x4 c0 = {0.f,0.f,0.f,0.f}, c1 = {0.f,0.f,0.f,0.f}, dn = {0.f,0.f,0.f,0.f};
    short8 bones;
#pragma unroll
    for (int e = 0; e < 8; ++e) bones[e] = (short)0x3F80;  // bf16 1.0

    auto stage = [&](int slot, int s) {   // 4 issues, wave-private dest
#pragma unroll
        for (int k = 0; k < 4; ++k)
            __builtin_amdgcn_global_load_lds(g[k] + s * JSTEP,
                                             &adjb[head][slot][k * 4 * 64], 16, 0, 0);
    };
    auto compute = [&](const unsigned int* buf, const SR& S) {
#pragma unroll
        for (int ks = 0; ks < 2; ++ks) {
            const u32x4 ba = ks ? S.bd10 : S.bd00;
            const u32x4 bb = ks ? S.bd11 : S.bd01;
            const short8 tA = __builtin_bit_cast(short8, ks ? S.h0k1 : S.h0k0);
            const short8 tB = __builtin_bit_cast(short8, ks ? S.h1k1 : S.h1k0);
            const int cb = ks * 8 + grp * 2;
            const i32x4 q0 = *(const i32x4*)&buf[li * 64 + ((cb) ^ li) * 4];
            const i32x4 q1 = *(const i32x4*)&buf[li * 64 + ((cb + 1) ^ li) * 4];
            const short8 A = buildQ(R0, ba, bb, q0, q1);
            c0 = __builtin_amdgcn_mfma_f32_16x16x32_bf16(A, tA, c0, 0, 0, 0);
            c1 = __builtin_amdgcn_mfma_f32_16x16x32_bf16(A, tB, c1, 0, 0, 0);
            dn = __builtin_amdgcn_mfma_f32_16x16x32_bf16(A, bones, dn, 0, 0, 0);
        }
    };

    SR S0, S1;
    // prologue: S0 + adj(0) drained; adj(1) left in flight
    LOADR(S0, 0);
    __builtin_amdgcn_sched_barrier(0);
    stage(0, 0);
    __builtin_amdgcn_sched_barrier(0);
    stage(1, 1);
    __builtin_amdgcn_sched_barrier(0);
    asm volatile("s_waitcnt vmcnt(4)" ::: "memory");   // S0 + stage(0) done
    LAUNDER(S0);
    __builtin_amdgcn_sched_barrier(0);

#pragma unroll
    for (int t = 0; t < NSTEPS; ++t) {
        SR& Scur = (t & 1) ? S1 : S0;
        SR& Snxt = (t & 1) ? S0 : S1;
        if (t + 1 < NSTEPS) { LOADR(Snxt, (t + 1) * JSTEP); }
        __builtin_amdgcn_sched_barrier(0);
        if (t + 2 < NSTEPS) stage((t + 2) % 3, t + 2);
        __builtin_amdgcn_sched_barrier(0);

        compute(&adjb[head][t % 3][0], Scur);

        if (t + 1 < NSTEPS) {
            if (t + 2 < NSTEPS) {
                // outstanding: stage(t+1)[4 oldest], LOADR(t+1)[8], stage(t+2)[4]
                asm volatile("s_waitcnt vmcnt(4)" ::: "memory");
            } else {
                asm volatile("s_waitcnt vmcnt(0)" ::: "memory");
            }
            LAUNDER(Snxt);
            __builtin_amdgcn_sched_barrier(0);
        }
    }

    // Epilogue: C layout col=li, row=grp*4+r.
    const int r0 = ibase + grp * 4;
    float* nb = numer + head * 32 + li;
#pragma unroll
    for (int r = 0; r < 4; ++r) {
        atomicAdd(nb + (size_t)(r0 + r) * 128, c0[r]);
        atomicAdd(nb + (size_t)(r0 + r) * 128 + 16, c1[r]);
    }
    if (li == 0) {
#pragma unroll
        for (int r = 0; r < 4; ++r)
            atomicAdd(denom + (r0 + r) * 4 + head, dn[r]);
    }
}

// Kernel 4: out = numer / denom
__global__ __launch_bounds__(256) void k4_fin(const float* __restrict__ numer,
                                              const float* __restrict__ denom,
                                              float* __restrict__ out) {
    const int idx = blockIdx.x * 256 + threadIdx.x;
    const int node = idx >> 7;
    const int headc = (idx & 127) >> 5;
    out[idx] = numer[idx] / denom[node * 4 + headc];
}

extern "C" void kernel_launch(void* const* d_in, const int* in_sizes, int n_in,
                              void* d_out, int out_size, void* d_ws, size_t ws_size,
                              hipStream_t stream) {
    const float* x = (const float*)d_in[0];
    const int* adj = (const int*)d_in[1];
    const float* W = (const float*)d_in[2];
    const float* asrc = (const float*)d_in[3];
    const float* adst = (const float*)d_in[4];
    float* out = (float*)d_out;

    char* ws = (char*)d_ws;
    float* numer = (float*)ws;                                     // 2 MB
    float* denom = (float*)(ws + (size_t)2097152);                 // 64 KB
    float* Rt = (float*)(ws + (size_t)2097152 + 65536);            // 64 KB
    unsigned* BDt = (unsigned*)(ws + (size_t)2097152 + 131072);    // 64 KB
    unsigned short* hT = (unsigned short*)(ws + (size_t)2097152 + 196608);  // 1 MB

    (void)hipMemsetAsync(numer, 0, 2097152 + 65536, stream);       // zero accumulators
    k1_proj<<<256, 256, 0, stream>>>(x, W, asrc, adst, hT, Rt, BDt);
    k3_main<<<dim3(256, SJ), 256, 0, stream>>>(adj, hT, Rt, BDt, numer, denom);
    k4_fin<<<2048, 256, 0, stream>>>(numer, denom, out);
}

// Round 16
// 59.748 us; speedup vs baseline: 1.5253x; 1.1779x over previous
//
#include <hip/hip_runtime.h>
#include <hip/hip_bf16.h>

#define NN 4096
#define SJ 8
#define JCH (NN / SJ)        // 512
#define JSTEP 64
#define NSTEPS (JCH / JSTEP) // 8
#define LOG2E 1.44269504f

typedef __attribute__((ext_vector_type(4))) float f32x4;
typedef __attribute__((ext_vector_type(4))) int i32x4;
typedef __attribute__((ext_vector_type(4))) unsigned int u32x4;
typedef __attribute__((ext_vector_type(8))) short short8;

// packed bf16 pair: (lo=bf16(a), hi=bf16(b)) in one dword (v_cvt_pk_bf16_f32)
__device__ __forceinline__ unsigned pk2(float a, float b) {
    float2 t; t.x = a; t.y = b;
    __hip_bfloat162 h = __float22bfloat162_rn(t);
    unsigned r;
    __builtin_memcpy(&r, &h, 4);
    return r;
}

__device__ __forceinline__ short8 load8_bf(const float* __restrict__ p) {
    f32x4 a = *(const f32x4*)p;
    f32x4 b = *(const f32x4*)(p + 4);
    u32x4 v = {pk2(a[0], a[1]), pk2(a[2], a[3]), pk2(b[0], b[1]), pk2(b[2], b[3])};
    return __builtin_bit_cast(short8, v);
}

// Kernel 1: h = x @ W^T (bf16 MFMA). Epilogue:
//   Rt[h][i]  = exp(-0.8*es_i)   (f32; exp(es) factor cancels in softmax)
//   BDt[h][j] = pack_bf16(exp(ed_j), exp(0.2*ed_j))
//   hT[h*32+d][j] = bf16 h, transposed via per-wave LDS tile (coalesced stores)
__global__ __launch_bounds__(256) void k1_proj(
        const float* __restrict__ x, const float* __restrict__ W,
        const float* __restrict__ asrc, const float* __restrict__ adst,
        unsigned short* __restrict__ hT, float* __restrict__ Rt,
        unsigned* __restrict__ BDt) {
    __shared__ unsigned short ttile[4][32][16];   // 4 KB
    const int ibase = blockIdx.x * 16;
    const int w = threadIdx.x >> 6;
    const int lane = threadIdx.x & 63;
    const int grp = lane >> 4, li = lane & 15;

    const float* xrow = x + (ibase + li) * 128;
    const float* w0 = W + (w * 32 + li) * 128;
    const float* w1 = W + (w * 32 + 16 + li) * 128;

    f32x4 c0 = {0.f, 0.f, 0.f, 0.f}, c1 = {0.f, 0.f, 0.f, 0.f};
#pragma unroll
    for (int ko = 0; ko < 128; ko += 32) {
        const int kk = ko + grp * 8;
        short8 a = load8_bf(xrow + kk);
        short8 b0 = load8_bf(w0 + kk);
        short8 b1 = load8_bf(w1 + kk);
        c0 = __builtin_amdgcn_mfma_f32_16x16x32_bf16(a, b0, c0, 0, 0, 0);
        c1 = __builtin_amdgcn_mfma_f32_16x16x32_bf16(a, b1, c1, 0, 0, 0);
    }
    const float as0 = asrc[w * 32 + li], as1 = asrc[w * 32 + 16 + li];
    const float ad0 = adst[w * 32 + li], ad1 = adst[w * 32 + 16 + li];
    float pes[4], ped[4];
#pragma unroll
    for (int r = 0; r < 4; ++r) {
        pes[r] = c0[r] * as0 + c1[r] * as1;
        ped[r] = c0[r] * ad0 + c1[r] * ad1;
    }
#pragma unroll
    for (int m = 1; m < 16; m <<= 1) {
#pragma unroll
        for (int r = 0; r < 4; ++r) {
            pes[r] += __shfl_xor(pes[r], m);
            ped[r] += __shfl_xor(ped[r], m);
        }
    }
    if (li == 0) {
#pragma unroll
        for (int r = 0; r < 4; ++r) {
            const int row = ibase + grp * 4 + r;
            Rt[w * NN + row] = __builtin_amdgcn_exp2f(-0.8f * LOG2E * pes[r]);
            const float Bv = __builtin_amdgcn_exp2f(LOG2E * ped[r]);
            const float Dv = __builtin_amdgcn_exp2f(0.2f * LOG2E * ped[r]);
            BDt[w * NN + row] = pk2(Bv, Dv);
        }
    }
    unsigned short* tw = &ttile[w][0][0];
    {
        uint2 v0; v0.x = pk2(c0[0], c0[1]); v0.y = pk2(c0[2], c0[3]);
        uint2 v1; v1.x = pk2(c1[0], c1[1]); v1.y = pk2(c1[2], c1[3]);
        *(uint2*)&tw[li * 16 + grp * 4] = v0;
        *(uint2*)&tw[(li + 16) * 16 + grp * 4] = v1;
    }
    __syncthreads();
    const int d = lane >> 1, half = lane & 1;
    u32x4 v = *(const u32x4*)&ttile[w][d][half * 8];
    *(u32x4*)(hT + (size_t)(w * 32 + d) * NN + ibase + half * 8) = v;
}

// ---- inline-asm 16B loads (volatile: cannot be sunk/reordered vs each other) ----
__device__ __forceinline__ u32x4 gld0(const void* p) {
    u32x4 d; asm volatile("global_load_dwordx4 %0, %1, off" : "=&v"(d) : "v"(p)); return d;
}
__device__ __forceinline__ u32x4 gld16(const void* p) {
    u32x4 d; asm volatile("global_load_dwordx4 %0, %1, off offset:16" : "=&v"(d) : "v"(p)); return d;
}
__device__ __forceinline__ u32x4 gld64(const void* p) {
    u32x4 d; asm volatile("global_load_dwordx4 %0, %1, off offset:64" : "=&v"(d) : "v"(p)); return d;
}
__device__ __forceinline__ u32x4 gld128(const void* p) {
    u32x4 d; asm volatile("global_load_dwordx4 %0, %1, off offset:128" : "=&v"(d) : "v"(p)); return d;
}
__device__ __forceinline__ u32x4 gld144(const void* p) {
    u32x4 d; asm volatile("global_load_dwordx4 %0, %1, off offset:144" : "=&v"(d) : "v"(p)); return d;
}

// per-step table payload: 8 x u32x4 = 32 VGPR per slot (shared by 4 row-groups)
struct SR { u32x4 h0k0, h0k1, h1k0, h1k1, bd00, bd01, bd10, bd11; };

#define LOADR(dst, toff) do {                                             \
    (dst).h0k0 = gld0(h0b + (toff));  (dst).h0k1 = gld64(h0b + (toff));   \
    (dst).h1k0 = gld0(h1b + (toff));  (dst).h1k1 = gld64(h1b + (toff));   \
    (dst).bd00 = gld0(bd + (toff));   (dst).bd01 = gld16(bd + (toff));    \
    (dst).bd10 = gld128(bd + (toff)); (dst).bd11 = gld144(bd + (toff));   \
} while (0)

#define LAUNDER(s) asm volatile("" : "+v"((s).h0k0), "+v"((s).h0k1),      \
    "+v"((s).h1k0), "+v"((s).h1k1), "+v"((s).bd00), "+v"((s).bd01),       \
    "+v"((s).bd10), "+v"((s).bd11))

// q = adj * max(B, R*D) from packed bf16 {B,D} (proven math, f32 compute)
__device__ __forceinline__ short8 buildQ(float R, const u32x4 ba, const u32x4 bb,
                                         const i32x4 q0, const i32x4 q1) {
    float p[8];
#pragma unroll
    for (int e = 0; e < 4; ++e) {
        const unsigned v = ba[e];
        const float B = __builtin_bit_cast(float, v << 16);
        const float D = __builtin_bit_cast(float, v & 0xFFFF0000u);
        const float m = fmaxf(B, R * D);
        p[e] = __builtin_bit_cast(float, __builtin_bit_cast(unsigned, m) & (0u - (unsigned)q0[e]));
    }
#pragma unroll
    for (int e = 0; e < 4; ++e) {
        const unsigned v = bb[e];
        const float B = __builtin_bit_cast(float, v << 16);
        const float D = __builtin_bit_cast(float, v & 0xFFFF0000u);
        const float m = fmaxf(B, R * D);
        p[4 + e] = __builtin_bit_cast(float, __builtin_bit_cast(unsigned, m) & (0u - (unsigned)q1[e]));
    }
    u32x4 u = {pk2(p[0], p[1]), pk2(p[2], p[3]), pk2(p[4], p[5]), pk2(p[6], p[7])};
    return __builtin_bit_cast(short8, u);
}

// Kernel 3: grid (64 i-tiles of 64 rows, SJ) x 256 thr, wave = head.
// R11 schedule scaled 4x in compute: 64-row tile -> 4 row-groups per wave
// share one table-load set (~1100cy compute/step vs 12 loads/step).
// adj triple-buffered shared LDS (depth-2); tables 2 register slots (depth-1,
// asm + launder). In-order drain accounting per step (16 outstanding at wait):
//   [stage(t+1) 4 | LOADR(t+1) 8 | stage(t+2) 4] -> vmcnt(4) drains first 12.
__global__ __launch_bounds__(256) void k3_main(
        const int* __restrict__ adj, const unsigned short* __restrict__ hT,
        const float* __restrict__ Rt, const unsigned* __restrict__ BDt,
        float* __restrict__ numer, float* __restrict__ denom) {
    __shared__ unsigned int adjb[3][64 * 64];   // 3 x 16 KB

    const int ibase = blockIdx.x * 64;
    const int jstart = blockIdx.y * JCH;
    const int head = threadIdx.x >> 6;
    const int lane = threadIdx.x & 63;
    const int grp = lane >> 4, li = lane & 15;
    const int sub = lane >> 4, p = lane & 15;     // staging roles

    float Rv[4];
#pragma unroll
    for (int g = 0; g < 4; ++g) Rv[g] = Rt[head * NN + ibase + g * 16 + li];
    const unsigned short* h0b = hT + (size_t)(head * 32 + li) * NN + jstart + grp * 8;
    const unsigned short* h1b = h0b + (size_t)16 * NN;
    const unsigned* bd = BDt + head * NN + jstart + grp * 8;
    const unsigned int* adju = (const unsigned int*)adj;

    // staging: wave `head` stages rows head*16..+15 (4 issues x 4 rows); row r,
    // chunk-position p holds global chunk p ^ (r&15) (LDS linear per rule 21).
    const unsigned int* gs[4];
#pragma unroll
    for (int k = 0; k < 4; ++k) {
        const int r = head * 16 + k * 4 + sub;
        gs[k] = adju + (size_t)(ibase + r) * NN + jstart + (p ^ (r & 15)) * 4;
    }

    f32x4 c[4][2], dn[4];
#pragma unroll
    for (int g = 0; g < 4; ++g) {
        c[g][0] = f32x4{0.f,0.f,0.f,0.f};
        c[g][1] = f32x4{0.f,0.f,0.f,0.f};
        dn[g] = f32x4{0.f,0.f,0.f,0.f};
    }
    short8 bones;
#pragma unroll
    for (int e = 0; e < 8; ++e) bones[e] = (short)0x3F80;  // bf16 1.0

    auto stage = [&](int slot, int s) {   // 4 issues, shared dest
#pragma unroll
        for (int k = 0; k < 4; ++k)
            __builtin_amdgcn_global_load_lds(gs[k] + s * JSTEP,
                                             &adjb[slot][(head * 16 + k * 4) * 64], 16, 0, 0);
    };
    auto compute = [&](const unsigned int* buf, const SR& S) {
#pragma unroll
        for (int ks = 0; ks < 2; ++ks) {
            const u32x4 ba = ks ? S.bd10 : S.bd00;
            const u32x4 bb = ks ? S.bd11 : S.bd01;
            const short8 tA = __builtin_bit_cast(short8, ks ? S.h0k1 : S.h0k0);
            const short8 tB = __builtin_bit_cast(short8, ks ? S.h1k1 : S.h1k0);
            const int cb = ks * 8 + grp * 2;
#pragma unroll
            for (int g = 0; g < 4; ++g) {
                const int rr = g * 16 + li;
                const i32x4 q0 = *(const i32x4*)&buf[rr * 64 + ((cb) ^ li) * 4];
                const i32x4 q1 = *(const i32x4*)&buf[rr * 64 + ((cb + 1) ^ li) * 4];
                const short8 A = buildQ(Rv[g], ba, bb, q0, q1);
                c[g][0] = __builtin_amdgcn_mfma_f32_16x16x32_bf16(A, tA, c[g][0], 0, 0, 0);
                c[g][1] = __builtin_amdgcn_mfma_f32_16x16x32_bf16(A, tB, c[g][1], 0, 0, 0);
                dn[g] = __builtin_amdgcn_mfma_f32_16x16x32_bf16(A, bones, dn[g], 0, 0, 0);
            }
        }
    };

    SR S0, S1;
    // prologue: [stage(0) 4 | LOADR(S0) 8 | stage(1) 4] = 16 outstanding;
    // vmcnt(4) drains the first 12 (stage(0)+S0), leaves stage(1) in flight.
    stage(0, 0);
    __builtin_amdgcn_sched_barrier(0);
    LOADR(S0, 0);
    __builtin_amdgcn_sched_barrier(0);
    stage(1, 1);
    __builtin_amdgcn_sched_barrier(0);
    asm volatile("s_waitcnt vmcnt(4)" ::: "memory");
    LAUNDER(S0);
    __builtin_amdgcn_s_barrier();
    __builtin_amdgcn_sched_barrier(0);

#pragma unroll
    for (int t = 0; t < NSTEPS; ++t) {
        SR& Scur = (t & 1) ? S1 : S0;
        SR& Snxt = (t & 1) ? S0 : S1;
        if (t + 1 < NSTEPS) { LOADR(Snxt, (t + 1) * JSTEP); }
        __builtin_amdgcn_sched_barrier(0);
        if (t + 2 < NSTEPS) stage((t + 2) % 3, t + 2);
        __builtin_amdgcn_sched_barrier(0);

        compute(&adjb[t % 3][0], Scur);

        if (t + 1 < NSTEPS) {
            if (t + 2 < NSTEPS) {
                // queue: [stage(t+1) 4 | LOADR(t+1) 8 | stage(t+2) 4]
                asm volatile("s_waitcnt vmcnt(4)" ::: "memory");
            } else {
                asm volatile("s_waitcnt vmcnt(0)" ::: "memory");
            }
            LAUNDER(Snxt);
            __builtin_amdgcn_s_barrier();
            __builtin_amdgcn_sched_barrier(0);
        }
    }

    // Epilogue: C layout col=li, row=grp*4+r within each 16-row group.
    float* nb = numer + head * 32 + li;
#pragma unroll
    for (int g = 0; g < 4; ++g) {
        const int r0 = ibase + g * 16 + grp * 4;
#pragma unroll
        for (int r = 0; r < 4; ++r) {
            atomicAdd(nb + (size_t)(r0 + r) * 128, c[g][0][r]);
            atomicAdd(nb + (size_t)(r0 + r) * 128 + 16, c[g][1][r]);
        }
    }
    if (li == 0) {
#pragma unroll
        for (int g = 0; g < 4; ++g) {
            const int r0 = ibase + g * 16 + grp * 4;
#pragma unroll
            for (int r = 0; r < 4; ++r)
                atomicAdd(denom + (r0 + r) * 4 + head, dn[g][r]);
        }
    }
}

// Kernel 4: out = numer / denom
__global__ __launch_bounds__(256) void k4_fin(const float* __restrict__ numer,
                                              const float* __restrict__ denom,
                                              float* __restrict__ out) {
    const int idx = blockIdx.x * 256 + threadIdx.x;
    const int node = idx >> 7;
    const int headc = (idx & 127) >> 5;
    out[idx] = numer[idx] / denom[node * 4 + headc];
}

extern "C" void kernel_launch(void* const* d_in, const int* in_sizes, int n_in,
                              void* d_out, int out_size, void* d_ws, size_t ws_size,
                              hipStream_t stream) {
    const float* x = (const float*)d_in[0];
    const int* adj = (const int*)d_in[1];
    const float* W = (const float*)d_in[2];
    const float* asrc = (const float*)d_in[3];
    const float* adst = (const float*)d_in[4];
    float* out = (float*)d_out;

    char* ws = (char*)d_ws;
    float* numer = (float*)ws;                                     // 2 MB
    float* denom = (float*)(ws + (size_t)2097152);                 // 64 KB
    float* Rt = (float*)(ws + (size_t)2097152 + 65536);            // 64 KB
    unsigned* BDt = (unsigned*)(ws + (size_t)2097152 + 131072);    // 64 KB
    unsigned short* hT = (unsigned short*)(ws + (size_t)2097152 + 196608);  // 1 MB

    (void)hipMemsetAsync(numer, 0, 2097152 + 65536, stream);       // zero accumulators
    k1_proj<<<256, 256, 0, stream>>>(x, W, asrc, adst, hT, Rt, BDt);
    k3_main<<<dim3(64, SJ), 256, 0, stream>>>(adj, hT, Rt, BDt, numer, denom);
    k4_fin<<<2048, 256, 0, stream>>>(numer, denom, out);
}